// Round 5
// baseline (216.358 us; speedup 1.0000x reference)
//
#include <hip/hip_runtime.h>
#include <hip/hip_bf16.h>

#define N_NODES 100000
#define N_EDGES 1600000
#define IN_F 256
#define OUT_F 128

typedef __attribute__((ext_vector_type(8))) __bf16 bf16x8;
typedef __attribute__((ext_vector_type(4))) float f32x4;

// ---------- helpers ----------
__device__ __forceinline__ float bf16_lo(unsigned int p) {
    union { unsigned int i; float f; } u; u.i = p << 16; return u.f;
}
__device__ __forceinline__ float bf16_hi(unsigned int p) {
    union { unsigned int i; float f; } u; u.i = p & 0xffff0000u; return u.f;
}
__device__ __forceinline__ unsigned short f2bf(float f) {
    union { float f; unsigned int i; } u; u.f = f;
    unsigned int r = u.i + 0x7fff + ((u.i >> 16) & 1);   // RNE (finite data only)
    return (unsigned short)(r >> 16);
}

// ---------- kernel 0: W fp32 [K][N] -> bf16 transposed wt [N][K] ----------
__global__ __launch_bounds__(256) void wconv_kernel(
    const float* __restrict__ weight, unsigned short* __restrict__ wt) {
  int id = blockIdx.x * 256 + threadIdx.x;   // 32768 = 256*128
  int col = id & 127;
  int k   = id >> 7;
  wt[(size_t)col * IN_F + k] = f2bf(weight[(size_t)k * OUT_F + col]);
}

// ---------- kernel 1: support = X @ W via MFMA, bf16 sliced output ----------
// Output layout: 8 feature-group slices, slice g = [N_NODES][16 features] bf16
// (32 B per node per slice, slice-contiguous so each slice = 3.2 MB).
#define XS 72
#define WSS 72
__global__ __launch_bounds__(256) void gemm_xw_mfma(
    const float* __restrict__ x, const unsigned short* __restrict__ wt,
    unsigned int* __restrict__ support /* [8][N_NODES][8] uints */) {
  __shared__ unsigned short smem[13824];
  unsigned short* Xt = smem;           // [64][XS]
  unsigned short* Wt = smem + 4608;    // [128][WSS]

  const int tid  = threadIdx.x;
  const int w    = tid >> 6;
  const int lane = tid & 63;
  const int l15  = lane & 15;
  const int lhi  = lane >> 4;
  const int row0 = blockIdx.x * 64;

  f32x4 acc[8];
  #pragma unroll
  for (int nt = 0; nt < 8; ++nt) acc[nt] = (f32x4){0.f, 0.f, 0.f, 0.f};

  for (int ks = 0; ks < 4; ++ks) {
    {
      int r = tid >> 2;
      int srow = row0 + r; if (srow >= N_NODES) srow = N_NODES - 1;
      const float* xp = x + (size_t)srow * IN_F + ks * 64;
      #pragma unroll
      for (int i = 0; i < 4; ++i) {
        int f4 = (tid & 3) + i * 4;          // 0..15
        float4 v = *(const float4*)(xp + f4 * 4);
        ushort4 h;
        h.x = f2bf(v.x); h.y = f2bf(v.y); h.z = f2bf(v.z); h.w = f2bf(v.w);
        *(ushort4*)(&Xt[r * XS + f4 * 4]) = h;
      }
    }
    {
      int c = tid >> 1;
      const unsigned short* wp = wt + (size_t)c * IN_F + ks * 64;
      #pragma unroll
      for (int i = 0; i < 4; ++i) {
        int c8 = (tid & 1) * 4 + i;          // 0..7, 8 bf16 each
        uint4 v = *(const uint4*)(wp + c8 * 8);
        *(uint4*)(&Wt[c * WSS + c8 * 8]) = v;
      }
    }
    __syncthreads();
    #pragma unroll
    for (int kt = 0; kt < 2; ++kt) {
      bf16x8 a = *(const bf16x8*)(&Xt[(w * 16 + l15) * XS + kt * 32 + lhi * 8]);
      #pragma unroll
      for (int nt = 0; nt < 8; ++nt) {
        bf16x8 b = *(const bf16x8*)(&Wt[(nt * 16 + l15) * WSS + kt * 32 + lhi * 8]);
        acc[nt] = __builtin_amdgcn_mfma_f32_16x16x32_bf16(a, b, acc[nt], 0, 0, 0);
      }
    }
    __syncthreads();
  }

  // epilogue: acc -> LDS bf16 [64][128] -> sliced global store
  unsigned short* Ot = smem;   // reuse
  #pragma unroll
  for (int nt = 0; nt < 8; ++nt)
    #pragma unroll
    for (int r = 0; r < 4; ++r) {
      int orow = w * 16 + lhi * 4 + r;       // D row = (lane>>4)*4 + reg
      int ocol = nt * 16 + l15;              // D col = lane&15
      Ot[orow * 128 + ocol] = f2bf(acc[nt][r]);
    }
  __syncthreads();
  {
    int g  = tid & 7;        // feature group
    int rr = tid >> 3;       // 0..31 -> 2 rows each
    #pragma unroll
    for (int k = 0; k < 2; ++k) {
      int r = rr * 2 + k;
      int grow = row0 + r;
      if (grow < N_NODES) {
        const uint4* src = (const uint4*)(&Ot[r * 128 + g * 16]);
        uint4* dst = (uint4*)(support + ((size_t)g * N_NODES + grow) * 8);
        dst[0] = src[0]; dst[1] = src[1];
      }
    }
  }
}

// ---------- kernel 2: row_ptr via binary search (edge_row is sorted) ----------
__global__ __launch_bounds__(256) void rowptr_kernel(
    const int* __restrict__ edge_row, int* __restrict__ row_ptr) {
  int r = blockIdx.x * 256 + threadIdx.x;
  if (r > N_NODES) return;
  int lo = 0, hi = N_EDGES;
  while (lo < hi) {
    int mid = (lo + hi) >> 1;
    if (edge_row[mid] < r) lo = mid + 1; else hi = mid;
  }
  row_ptr[r] = lo;  // first edge with row >= r
}

// ---------- kernel 3: sliced CSR SpMM ----------
// group = blockIdx%8 -> one XCD per feature slice (3.2 MB, L2-resident).
// Wave = (row, group). 8 lanes per edge (32 B), 8 edges per gather instr,
// 4 independent gathers = 32 edges in flight.
__global__ __launch_bounds__(256) void spmm_kernel(
    const unsigned int* __restrict__ support,  // [8][N_NODES][8] uints
    const int* __restrict__ row_ptr,
    const int* __restrict__ edge_col,
    const float* __restrict__ edge_val,
    const float* __restrict__ bias,
    float* __restrict__ out) {
  const int bid = blockIdx.x;            // 200000 blocks
  const int g   = bid & 7;               // feature group (XCD-aligned)
  const int w   = threadIdx.x >> 6;
  int row = __builtin_amdgcn_readfirstlane((bid >> 3) * 4 + w);
  const int lane = threadIdx.x & 63;
  const int eoff = lane >> 3;            // edge slot 0..7
  const int fp   = lane & 7;             // feature pair 0..7

  const unsigned int* sl = support + (size_t)g * N_NODES * 8 + fp;

  int e   = row_ptr[row];
  int end = row_ptr[row + 1];
  float a0 = 0.f, a1 = 0.f;

  while (e < end) {
    const int endm1 = end - 1;
    int ei0 = e + eoff, ei1 = ei0 + 8, ei2 = ei0 + 16, ei3 = ei0 + 24;
    int j0 = ei0 < end ? ei0 : endm1;
    int j1 = ei1 < end ? ei1 : endm1;
    int j2 = ei2 < end ? ei2 : endm1;
    int j3 = ei3 < end ? ei3 : endm1;
    int c0 = edge_col[j0];
    int c1 = edge_col[j1];
    int c2 = edge_col[j2];
    int c3 = edge_col[j3];
    float v0 = ei0 < end ? edge_val[j0] : 0.f;
    float v1 = ei1 < end ? edge_val[j1] : 0.f;
    float v2 = ei2 < end ? edge_val[j2] : 0.f;
    float v3 = ei3 < end ? edge_val[j3] : 0.f;
    unsigned int s0 = sl[(size_t)c0 * 8];
    unsigned int s1 = sl[(size_t)c1 * 8];
    unsigned int s2 = sl[(size_t)c2 * 8];
    unsigned int s3 = sl[(size_t)c3 * 8];
    a0 += v0 * bf16_lo(s0); a1 += v0 * bf16_hi(s0);
    a0 += v1 * bf16_lo(s1); a1 += v1 * bf16_hi(s1);
    a0 += v2 * bf16_lo(s2); a1 += v2 * bf16_hi(s2);
    a0 += v3 * bf16_lo(s3); a1 += v3 * bf16_hi(s3);
    e += 32;
  }

  // reduce across the 8 edge slots
  a0 += __shfl_xor(a0,  8, 64); a1 += __shfl_xor(a1,  8, 64);
  a0 += __shfl_xor(a0, 16, 64); a1 += __shfl_xor(a1, 16, 64);
  a0 += __shfl_xor(a0, 32, 64); a1 += __shfl_xor(a1, 32, 64);

  if (lane < 8) {
    float2 b = *(const float2*)(bias + g * 16 + fp * 2);
    float2 o; o.x = a0 + b.x; o.y = a1 + b.y;
    *(float2*)(out + (size_t)row * OUT_F + g * 16 + fp * 2) = o;
  }
}

// ---------- launch ----------
extern "C" void kernel_launch(void* const* d_in, const int* in_sizes, int n_in,
                              void* d_out, int out_size, void* d_ws, size_t ws_size,
                              hipStream_t stream) {
  const float* x        = (const float*)d_in[0];
  const int*   edge_row = (const int*)  d_in[1];
  const int*   edge_col = (const int*)  d_in[2];
  const float* edge_val = (const float*)d_in[3];
  const float* weight   = (const float*)d_in[4];
  const float* bias     = (const float*)d_in[5];
  float* out = (float*)d_out;

  unsigned char* ws = (unsigned char*)d_ws;
  size_t support_bytes = (size_t)N_NODES * OUT_F * 2;            // 25.6 MB bf16
  unsigned int* support = (unsigned int*)ws;
  size_t rp_off = (support_bytes + 255) & ~(size_t)255;
  int* row_ptr = (int*)(ws + rp_off);
  size_t wt_off = (rp_off + (size_t)(N_NODES + 1) * 4 + 255) & ~(size_t)255;
  unsigned short* wt = (unsigned short*)(ws + wt_off);

  hipLaunchKernelGGL(rowptr_kernel, dim3((N_NODES + 1 + 255) / 256), dim3(256), 0, stream,
                     edge_row, row_ptr);
  hipLaunchKernelGGL(wconv_kernel, dim3(128), dim3(256), 0, stream,
                     weight, wt);
  hipLaunchKernelGGL(gemm_xw_mfma, dim3((N_NODES + 63) / 64), dim3(256), 0, stream,
                     x, wt, support);
  hipLaunchKernelGGL(spmm_kernel, dim3((N_NODES / 4) * 8), dim3(256), 0, stream,
                     support, row_ptr, edge_col, edge_val, bias, out);
}

// Round 6
// 200.105 us; speedup vs baseline: 1.0812x; 1.0812x over previous
//
#include <hip/hip_runtime.h>
#include <hip/hip_bf16.h>

#define N_NODES 100000
#define N_EDGES 1600000
#define IN_F 256
#define OUT_F 128

typedef __attribute__((ext_vector_type(8))) __bf16 bf16x8;
typedef __attribute__((ext_vector_type(4))) float f32x4;

// ---------- helpers ----------
__device__ __forceinline__ float bf16_lo(unsigned int p) {
    union { unsigned int i; float f; } u; u.i = p << 16; return u.f;
}
__device__ __forceinline__ float bf16_hi(unsigned int p) {
    union { unsigned int i; float f; } u; u.i = p & 0xffff0000u; return u.f;
}
__device__ __forceinline__ unsigned short f2bf(float f) {
    union { float f; unsigned int i; } u; u.f = f;
    unsigned int r = u.i + 0x7fff + ((u.i >> 16) & 1);   // RNE (finite data only)
    return (unsigned short)(r >> 16);
}

// ---------- kernel 0: W fp32 [K][N] -> bf16 transposed wt [N][K] ----------
__global__ __launch_bounds__(256) void wconv_kernel(
    const float* __restrict__ weight, unsigned short* __restrict__ wt) {
  int id = blockIdx.x * 256 + threadIdx.x;   // 32768 = 256*128
  int col = id & 127;
  int k   = id >> 7;
  wt[(size_t)col * IN_F + k] = f2bf(weight[(size_t)k * OUT_F + col]);
}

// ---------- kernel 1: support = X @ W via MFMA, bf16 sliced output ----------
// Output layout: 8 feature-group slices, slice g = [N_NODES][16 features] bf16
// (32 B per node per slice, slice-contiguous so each slice = 3.2 MB, L2-fit).
#define XS 72
#define WSS 72
__global__ __launch_bounds__(256) void gemm_xw_mfma(
    const float* __restrict__ x, const unsigned short* __restrict__ wt,
    unsigned int* __restrict__ support /* [8][N_NODES][8] uints */) {
  __shared__ unsigned short smem[13824];
  unsigned short* Xt = smem;           // [64][XS]
  unsigned short* Wt = smem + 4608;    // [128][WSS]

  const int tid  = threadIdx.x;
  const int w    = tid >> 6;
  const int lane = tid & 63;
  const int l15  = lane & 15;
  const int lhi  = lane >> 4;
  const int row0 = blockIdx.x * 64;

  f32x4 acc[8];
  #pragma unroll
  for (int nt = 0; nt < 8; ++nt) acc[nt] = (f32x4){0.f, 0.f, 0.f, 0.f};

  for (int ks = 0; ks < 4; ++ks) {
    {
      int r = tid >> 2;
      int srow = row0 + r; if (srow >= N_NODES) srow = N_NODES - 1;
      const float* xp = x + (size_t)srow * IN_F + ks * 64;
      #pragma unroll
      for (int i = 0; i < 4; ++i) {
        int f4 = (tid & 3) + i * 4;          // 0..15
        float4 v = *(const float4*)(xp + f4 * 4);
        ushort4 h;
        h.x = f2bf(v.x); h.y = f2bf(v.y); h.z = f2bf(v.z); h.w = f2bf(v.w);
        *(ushort4*)(&Xt[r * XS + f4 * 4]) = h;
      }
    }
    {
      int c = tid >> 1;
      const unsigned short* wp = wt + (size_t)c * IN_F + ks * 64;
      #pragma unroll
      for (int i = 0; i < 4; ++i) {
        int c8 = (tid & 1) * 4 + i;          // 0..7, 8 bf16 each
        uint4 v = *(const uint4*)(wp + c8 * 8);
        *(uint4*)(&Wt[c * WSS + c8 * 8]) = v;
      }
    }
    __syncthreads();
    #pragma unroll
    for (int kt = 0; kt < 2; ++kt) {
      bf16x8 a = *(const bf16x8*)(&Xt[(w * 16 + l15) * XS + kt * 32 + lhi * 8]);
      #pragma unroll
      for (int nt = 0; nt < 8; ++nt) {
        bf16x8 b = *(const bf16x8*)(&Wt[(nt * 16 + l15) * WSS + kt * 32 + lhi * 8]);
        acc[nt] = __builtin_amdgcn_mfma_f32_16x16x32_bf16(a, b, acc[nt], 0, 0, 0);
      }
    }
    __syncthreads();
  }

  // epilogue: acc -> LDS bf16 [64][128] -> sliced global store
  unsigned short* Ot = smem;   // reuse
  #pragma unroll
  for (int nt = 0; nt < 8; ++nt)
    #pragma unroll
    for (int r = 0; r < 4; ++r) {
      int orow = w * 16 + lhi * 4 + r;       // D row = (lane>>4)*4 + reg
      int ocol = nt * 16 + l15;              // D col = lane&15
      Ot[orow * 128 + ocol] = f2bf(acc[nt][r]);
    }
  __syncthreads();
  {
    int g  = tid & 7;        // feature group
    int rr = tid >> 3;       // 0..31 -> 2 rows each
    #pragma unroll
    for (int k = 0; k < 2; ++k) {
      int r = rr * 2 + k;
      int grow = row0 + r;
      if (grow < N_NODES) {
        const uint4* src = (const uint4*)(&Ot[r * 128 + g * 16]);
        uint4* dst = (uint4*)(support + ((size_t)g * N_NODES + grow) * 8);
        dst[0] = src[0]; dst[1] = src[1];
      }
    }
  }
}

// ---------- kernel 2: row_ptr via binary search (edge_row is sorted) ----------
__global__ __launch_bounds__(256) void rowptr_kernel(
    const int* __restrict__ edge_row, int* __restrict__ row_ptr) {
  int r = blockIdx.x * 256 + threadIdx.x;
  if (r > N_NODES) return;
  int lo = 0, hi = N_EDGES;
  while (lo < hi) {
    int mid = (lo + hi) >> 1;
    if (edge_row[mid] < r) lo = mid + 1; else hi = mid;
  }
  row_ptr[r] = lo;  // first edge with row >= r
}

// ---------- kernel 3: sliced CSR SpMM, 64-row tiles ----------
// block = (64-row tile, group g=bid&7 -> XCD-pinned L2-resident slice).
// row_ptr tile staged in LDS once. Wave walks 16 rows; per row-iteration one
// gather instruction covers 16 edges x uint2 (8 B/lane), 4 accumulators,
// shfl-reduce over the 16 edge slots, float4 store by lanes 0..3.
__global__ __launch_bounds__(256) void spmm_kernel(
    const unsigned int* __restrict__ support,  // [8][N_NODES][8] uints
    const int* __restrict__ row_ptr,
    const int* __restrict__ edge_col,
    const float* __restrict__ edge_val,
    const float* __restrict__ bias,
    float* __restrict__ out) {
  __shared__ int rp[65];
  const int bid = blockIdx.x;
  const int g   = bid & 7;               // feature group (XCD round-robin)
  const int r0  = (bid >> 3) * 64;
  const int tid = threadIdx.x;

  if (tid < 65) {
    int rr = r0 + tid;
    rp[tid] = row_ptr[rr <= N_NODES ? rr : N_NODES];
  }
  __syncthreads();

  const int w    = tid >> 6;
  const int lane = tid & 63;
  const int eoff = lane >> 2;            // edge slot 0..15
  const int fp   = lane & 3;             // uint-pair 0..3 (4 features)
  const unsigned int* sl = support + (size_t)g * (N_NODES * 8) + fp * 2;
  const float4 b = *(const float4*)(bias + g * 16 + fp * 4);

  #pragma unroll 1
  for (int i = 0; i < 16; ++i) {
    int r   = w * 16 + i;                // 0..63 within tile
    int row = r0 + r;
    if (row >= N_NODES) break;
    int s = __builtin_amdgcn_readfirstlane(rp[r]);
    int t = __builtin_amdgcn_readfirstlane(rp[r + 1]);

    float a0 = 0.f, a1 = 0.f, a2 = 0.f, a3 = 0.f;
    for (int e = s; e < t; e += 16) {
      int  ei   = e + eoff;
      bool live = ei < t;
      int  j    = live ? ei : 0;
      int   c = edge_col[j];
      float v = live ? edge_val[j] : 0.f;
      uint2 sv = *(const uint2*)(sl + (size_t)c * 8);
      a0 += v * bf16_lo(sv.x); a1 += v * bf16_hi(sv.x);
      a2 += v * bf16_lo(sv.y); a3 += v * bf16_hi(sv.y);
    }
    // reduce across the 16 edge slots (lane bits 2..5)
    #pragma unroll
    for (int off = 4; off <= 32; off <<= 1) {
      a0 += __shfl_xor(a0, off, 64);
      a1 += __shfl_xor(a1, off, 64);
      a2 += __shfl_xor(a2, off, 64);
      a3 += __shfl_xor(a3, off, 64);
    }
    if (eoff == 0) {
      float4 o;
      o.x = a0 + b.x; o.y = a1 + b.y; o.z = a2 + b.z; o.w = a3 + b.w;
      *(float4*)(out + (size_t)row * OUT_F + g * 16 + fp * 4) = o;
    }
  }
}

// ---------- launch ----------
extern "C" void kernel_launch(void* const* d_in, const int* in_sizes, int n_in,
                              void* d_out, int out_size, void* d_ws, size_t ws_size,
                              hipStream_t stream) {
  const float* x        = (const float*)d_in[0];
  const int*   edge_row = (const int*)  d_in[1];
  const int*   edge_col = (const int*)  d_in[2];
  const float* edge_val = (const float*)d_in[3];
  const float* weight   = (const float*)d_in[4];
  const float* bias     = (const float*)d_in[5];
  float* out = (float*)d_out;

  unsigned char* ws = (unsigned char*)d_ws;
  size_t support_bytes = (size_t)N_NODES * OUT_F * 2;            // 25.6 MB bf16
  unsigned int* support = (unsigned int*)ws;
  size_t rp_off = (support_bytes + 255) & ~(size_t)255;
  int* row_ptr = (int*)(ws + rp_off);
  size_t wt_off = (rp_off + (size_t)(N_NODES + 1) * 4 + 255) & ~(size_t)255;
  unsigned short* wt = (unsigned short*)(ws + wt_off);

  hipLaunchKernelGGL(rowptr_kernel, dim3((N_NODES + 1 + 255) / 256), dim3(256), 0, stream,
                     edge_row, row_ptr);
  hipLaunchKernelGGL(wconv_kernel, dim3(128), dim3(256), 0, stream,
                     weight, wt);
  hipLaunchKernelGGL(gemm_xw_mfma, dim3((N_NODES + 63) / 64), dim3(256), 0, stream,
                     x, wt, support);
  hipLaunchKernelGGL(spmm_kernel, dim3(((N_NODES + 63) / 64) * 8), dim3(256), 0, stream,
                     support, row_ptr, edge_col, edge_val, bias, out);
}

// Round 7
// 161.485 us; speedup vs baseline: 1.3398x; 1.2392x over previous
//
#include <hip/hip_runtime.h>
#include <hip/hip_bf16.h>

#define N_NODES 100000
#define N_EDGES 1600000
#define IN_F 256
#define OUT_F 128

typedef __attribute__((ext_vector_type(8))) __bf16 bf16x8;
typedef __attribute__((ext_vector_type(4))) float f32x4;

// ---------- helpers ----------
__device__ __forceinline__ float bf16_lo(unsigned int p) {
    union { unsigned int i; float f; } u; u.i = p << 16; return u.f;
}
__device__ __forceinline__ float bf16_hi(unsigned int p) {
    union { unsigned int i; float f; } u; u.i = p & 0xffff0000u; return u.f;
}
__device__ __forceinline__ unsigned short f2bf(float f) {
    union { float f; unsigned int i; } u; u.f = f;
    unsigned int r = u.i + 0x7fff + ((u.i >> 16) & 1);   // RNE (finite data only)
    return (unsigned short)(r >> 16);
}

// ---------- kernel 0: W fp32 [K][N] -> bf16 transposed wt [N][K] ----------
__global__ __launch_bounds__(256) void wconv_kernel(
    const float* __restrict__ weight, unsigned short* __restrict__ wt) {
  int id = blockIdx.x * 256 + threadIdx.x;   // 32768 = 256*128
  int col = id & 127;
  int k   = id >> 7;
  wt[(size_t)col * IN_F + k] = f2bf(weight[(size_t)k * OUT_F + col]);
}

// ---------- kernel 1: support = X @ W via MFMA, bf16 sliced output ----------
// Output layout: 8 feature-group slices, slice g = [N_NODES][16 features] bf16
// (32 B per node per slice, slice-contiguous so each slice = 3.2 MB, L2-fit).
#define XS 72
#define WSS 72
__global__ __launch_bounds__(256) void gemm_xw_mfma(
    const float* __restrict__ x, const unsigned short* __restrict__ wt,
    unsigned int* __restrict__ support /* [8][N_NODES][8] uints */) {
  __shared__ unsigned short smem[13824];
  unsigned short* Xt = smem;           // [64][XS]
  unsigned short* Wt = smem + 4608;    // [128][WSS]

  const int tid  = threadIdx.x;
  const int w    = tid >> 6;
  const int lane = tid & 63;
  const int l15  = lane & 15;
  const int lhi  = lane >> 4;
  const int row0 = blockIdx.x * 64;

  f32x4 acc[8];
  #pragma unroll
  for (int nt = 0; nt < 8; ++nt) acc[nt] = (f32x4){0.f, 0.f, 0.f, 0.f};

  for (int ks = 0; ks < 4; ++ks) {
    {
      int r = tid >> 2;
      int srow = row0 + r; if (srow >= N_NODES) srow = N_NODES - 1;
      const float* xp = x + (size_t)srow * IN_F + ks * 64;
      #pragma unroll
      for (int i = 0; i < 4; ++i) {
        int f4 = (tid & 3) + i * 4;          // 0..15
        float4 v = *(const float4*)(xp + f4 * 4);
        ushort4 h;
        h.x = f2bf(v.x); h.y = f2bf(v.y); h.z = f2bf(v.z); h.w = f2bf(v.w);
        *(ushort4*)(&Xt[r * XS + f4 * 4]) = h;
      }
    }
    {
      int c = tid >> 1;
      const unsigned short* wp = wt + (size_t)c * IN_F + ks * 64;
      #pragma unroll
      for (int i = 0; i < 4; ++i) {
        int c8 = (tid & 1) * 4 + i;          // 0..7, 8 bf16 each
        uint4 v = *(const uint4*)(wp + c8 * 8);
        *(uint4*)(&Wt[c * WSS + c8 * 8]) = v;
      }
    }
    __syncthreads();
    #pragma unroll
    for (int kt = 0; kt < 2; ++kt) {
      bf16x8 a = *(const bf16x8*)(&Xt[(w * 16 + l15) * XS + kt * 32 + lhi * 8]);
      #pragma unroll
      for (int nt = 0; nt < 8; ++nt) {
        bf16x8 b = *(const bf16x8*)(&Wt[(nt * 16 + l15) * WSS + kt * 32 + lhi * 8]);
        acc[nt] = __builtin_amdgcn_mfma_f32_16x16x32_bf16(a, b, acc[nt], 0, 0, 0);
      }
    }
    __syncthreads();
  }

  // epilogue: acc -> LDS bf16 [64][128] -> sliced global store
  unsigned short* Ot = smem;   // reuse
  #pragma unroll
  for (int nt = 0; nt < 8; ++nt)
    #pragma unroll
    for (int r = 0; r < 4; ++r) {
      int orow = w * 16 + lhi * 4 + r;       // D row = (lane>>4)*4 + reg
      int ocol = nt * 16 + l15;              // D col = lane&15
      Ot[orow * 128 + ocol] = f2bf(acc[nt][r]);
    }
  __syncthreads();
  {
    int g  = tid & 7;        // feature group
    int rr = tid >> 3;       // 0..31 -> 2 rows each
    #pragma unroll
    for (int k = 0; k < 2; ++k) {
      int r = rr * 2 + k;
      int grow = row0 + r;
      if (grow < N_NODES) {
        const uint4* src = (const uint4*)(&Ot[r * 128 + g * 16]);
        uint4* dst = (uint4*)(support + ((size_t)g * N_NODES + grow) * 8);
        dst[0] = src[0]; dst[1] = src[1];
      }
    }
  }
}

// ---------- kernel 2: row_ptr via binary search (edge_row is sorted) ----------
__global__ __launch_bounds__(256) void rowptr_kernel(
    const int* __restrict__ edge_row, int* __restrict__ row_ptr) {
  int r = blockIdx.x * 256 + threadIdx.x;
  if (r > N_NODES) return;
  int lo = 0, hi = N_EDGES;
  while (lo < hi) {
    int mid = (lo + hi) >> 1;
    if (edge_row[mid] < r) lo = mid + 1; else hi = mid;
  }
  row_ptr[r] = lo;  // first edge with row >= r
}

// ---------- kernel 3: sliced CSR SpMM, 4 rows in parallel per wave ----------
// block = (64-row tile, group g=bid&7 -> XCD-pinned L2-resident 3.2MB slice).
// lane = rslot(2b hi) | eslot(2b) | fp(2b): 4 rows x 4 edge-slots x 4
// feature-pairs. Per iteration one gather covers 16 edges (4 per row).
// Reduce = 2 shfl levels per 4 rows. Trip count wave-uniform via shfl-max.
__global__ __launch_bounds__(256) void spmm_kernel(
    const unsigned int* __restrict__ support,  // [8][N_NODES][8] uints
    const int* __restrict__ row_ptr,
    const int* __restrict__ edge_col,
    const float* __restrict__ edge_val,
    const float* __restrict__ bias,
    float* __restrict__ out) {
  __shared__ int rp[65];
  const int bid = blockIdx.x;
  const int g   = bid & 7;               // feature group (XCD round-robin)
  const int r0  = (bid >> 3) * 64;
  const int tid = threadIdx.x;

  if (tid < 65) {
    int rr = r0 + tid;
    rp[tid] = row_ptr[rr <= N_NODES ? rr : N_NODES];
  }
  __syncthreads();

  const int w     = tid >> 6;            // wave 0..3
  const int lane  = tid & 63;
  const int rslot = lane >> 4;           // row slot 0..3
  const int eslot = (lane >> 2) & 3;     // edge slot 0..3
  const int fp    = lane & 3;            // uint-pair 0..3 (4 features)

  const unsigned int* sl = support + (size_t)g * (N_NODES * 8) + fp * 2;
  const float4 bv = *(const float4*)(bias + g * 16 + fp * 4);

  #pragma unroll 1
  for (int i = 0; i < 4; ++i) {
    int r   = w * 16 + i * 4 + rslot;    // 0..63 within tile
    int row = r0 + r;
    int s = rp[r];
    int t = rp[r + 1];
    int deg = t - s;
    int m = max(deg, __shfl_xor(deg, 16, 64));
    m = max(m, __shfl_xor(m, 32, 64));   // wave-uniform max degree

    float a0 = 0.f, a1 = 0.f, a2 = 0.f, a3 = 0.f;
    for (int it = 0; it < m; it += 4) {
      int  ei   = s + it + eslot;
      bool live = ei < t;
      int  j    = live ? ei : 0;
      int   c = edge_col[j];
      float v = live ? edge_val[j] : 0.f;
      uint2 sv = *(const uint2*)(sl + (size_t)c * 8);
      a0 += v * bf16_lo(sv.x); a1 += v * bf16_hi(sv.x);
      a2 += v * bf16_lo(sv.y); a3 += v * bf16_hi(sv.y);
    }
    // reduce across the 4 edge slots (lane bits 2..3)
    a0 += __shfl_xor(a0, 4, 64); a1 += __shfl_xor(a1, 4, 64);
    a2 += __shfl_xor(a2, 4, 64); a3 += __shfl_xor(a3, 4, 64);
    a0 += __shfl_xor(a0, 8, 64); a1 += __shfl_xor(a1, 8, 64);
    a2 += __shfl_xor(a2, 8, 64); a3 += __shfl_xor(a3, 8, 64);

    if (eslot == 0 && row < N_NODES) {
      float4 o;
      o.x = a0 + bv.x; o.y = a1 + bv.y; o.z = a2 + bv.z; o.w = a3 + bv.w;
      *(float4*)(out + (size_t)row * OUT_F + g * 16 + fp * 4) = o;
    }
  }
}

// ---------- launch ----------
extern "C" void kernel_launch(void* const* d_in, const int* in_sizes, int n_in,
                              void* d_out, int out_size, void* d_ws, size_t ws_size,
                              hipStream_t stream) {
  const float* x        = (const float*)d_in[0];
  const int*   edge_row = (const int*)  d_in[1];
  const int*   edge_col = (const int*)  d_in[2];
  const float* edge_val = (const float*)d_in[3];
  const float* weight   = (const float*)d_in[4];
  const float* bias     = (const float*)d_in[5];
  float* out = (float*)d_out;

  unsigned char* ws = (unsigned char*)d_ws;
  size_t support_bytes = (size_t)N_NODES * OUT_F * 2;            // 25.6 MB bf16
  unsigned int* support = (unsigned int*)ws;
  size_t rp_off = (support_bytes + 255) & ~(size_t)255;
  int* row_ptr = (int*)(ws + rp_off);
  size_t wt_off = (rp_off + (size_t)(N_NODES + 1) * 4 + 255) & ~(size_t)255;
  unsigned short* wt = (unsigned short*)(ws + wt_off);

  hipLaunchKernelGGL(rowptr_kernel, dim3((N_NODES + 1 + 255) / 256), dim3(256), 0, stream,
                     edge_row, row_ptr);
  hipLaunchKernelGGL(wconv_kernel, dim3(128), dim3(256), 0, stream,
                     weight, wt);
  hipLaunchKernelGGL(gemm_xw_mfma, dim3((N_NODES + 63) / 64), dim3(256), 0, stream,
                     x, wt, support);
  hipLaunchKernelGGL(spmm_kernel, dim3(((N_NODES + 63) / 64) * 8), dim3(256), 0, stream,
                     support, row_ptr, edge_col, edge_val, bias, out);
}

// Round 8
// 87.484 us; speedup vs baseline: 2.4731x; 1.8459x over previous
//
#include <hip/hip_runtime.h>
#include <hip/hip_bf16.h>

#define N_NODES 100000
#define N_EDGES 1600000
#define IN_F 256
#define OUT_F 128

typedef __attribute__((ext_vector_type(8))) __bf16 bf16x8;
typedef __attribute__((ext_vector_type(4))) float f32x4;

__device__ __forceinline__ unsigned short f2bf(float f) {
    union { float f; unsigned int i; } u; u.f = f;
    unsigned int r = u.i + 0x7fff + ((u.i >> 16) & 1);   // RNE (finite data only)
    return (unsigned short)(r >> 16);
}

// ---------- kernel 0: W fp32 [K][N] -> bf16 transposed wt [N][K] ----------
__global__ __launch_bounds__(256) void wconv_kernel(
    const float* __restrict__ weight, unsigned short* __restrict__ wt) {
  int id = blockIdx.x * 256 + threadIdx.x;   // 32768 = 256*128
  int col = id & 127;
  int k   = id >> 7;
  wt[(size_t)col * IN_F + k] = f2bf(weight[(size_t)k * OUT_F + col]);
}

// ---------- kernel 1: support = X @ W via MFMA -> int8 + per-row scale ----
// int8 row layout is PERMUTED: byte b of a row holds col (b&7)*16 + (b>>3),
// so each MFMA lane (holding cols nt*16+l15, nt=0..7) stores its 8 bytes
// contiguously at byte offset l15*8. spmm un-permutes on output.
#define XS 72
#define WSS 72
__global__ __launch_bounds__(256) void gemm_xw_mfma(
    const float* __restrict__ x, const unsigned short* __restrict__ wt,
    unsigned char* __restrict__ support_q /* [N_NODES][128] int8 */,
    float* __restrict__ scales /* [N_NODES] */) {
  __shared__ unsigned short smem[13824];
  unsigned short* Xt = smem;           // [64][XS]
  unsigned short* Wt = smem + 4608;    // [128][WSS]

  const int tid  = threadIdx.x;
  const int w    = tid >> 6;
  const int lane = tid & 63;
  const int l15  = lane & 15;
  const int lhi  = lane >> 4;
  const int row0 = blockIdx.x * 64;

  f32x4 acc[8];
  #pragma unroll
  for (int nt = 0; nt < 8; ++nt) acc[nt] = (f32x4){0.f, 0.f, 0.f, 0.f};

  for (int ks = 0; ks < 4; ++ks) {
    {
      int r = tid >> 2;
      int srow = row0 + r; if (srow >= N_NODES) srow = N_NODES - 1;
      const float* xp = x + (size_t)srow * IN_F + ks * 64;
      #pragma unroll
      for (int i = 0; i < 4; ++i) {
        int f4 = (tid & 3) + i * 4;          // 0..15
        float4 v = *(const float4*)(xp + f4 * 4);
        ushort4 h;
        h.x = f2bf(v.x); h.y = f2bf(v.y); h.z = f2bf(v.z); h.w = f2bf(v.w);
        *(ushort4*)(&Xt[r * XS + f4 * 4]) = h;
      }
    }
    {
      int c = tid >> 1;
      const unsigned short* wp = wt + (size_t)c * IN_F + ks * 64;
      #pragma unroll
      for (int i = 0; i < 4; ++i) {
        int c8 = (tid & 1) * 4 + i;          // 0..7, 8 bf16 each
        uint4 v = *(const uint4*)(wp + c8 * 8);
        *(uint4*)(&Wt[c * WSS + c8 * 8]) = v;
      }
    }
    __syncthreads();
    #pragma unroll
    for (int kt = 0; kt < 2; ++kt) {
      bf16x8 a = *(const bf16x8*)(&Xt[(w * 16 + l15) * XS + kt * 32 + lhi * 8]);
      #pragma unroll
      for (int nt = 0; nt < 8; ++nt) {
        bf16x8 b = *(const bf16x8*)(&Wt[(nt * 16 + l15) * WSS + kt * 32 + lhi * 8]);
        acc[nt] = __builtin_amdgcn_mfma_f32_16x16x32_bf16(a, b, acc[nt], 0, 0, 0);
      }
    }
    __syncthreads();
  }

  // ---- epilogue: per-row absmax -> int8 quant -> permuted-contiguous store
  float m0 = 0.f, m1 = 0.f, m2 = 0.f, m3 = 0.f;
  #pragma unroll
  for (int nt = 0; nt < 8; ++nt) {
    m0 = fmaxf(m0, fabsf(acc[nt][0]));
    m1 = fmaxf(m1, fabsf(acc[nt][1]));
    m2 = fmaxf(m2, fabsf(acc[nt][2]));
    m3 = fmaxf(m3, fabsf(acc[nt][3]));
  }
  #pragma unroll
  for (int off = 1; off <= 8; off <<= 1) {
    m0 = fmaxf(m0, __shfl_xor(m0, off, 64));
    m1 = fmaxf(m1, __shfl_xor(m1, off, 64));
    m2 = fmaxf(m2, __shfl_xor(m2, off, 64));
    m3 = fmaxf(m3, __shfl_xor(m3, off, 64));
  }
  // rows w*16 + lhi*4 + r, r=0..3; m replicated across l15
  #pragma unroll
  for (int r = 0; r < 4; ++r) {
    float m = (r == 0) ? m0 : (r == 1) ? m1 : (r == 2) ? m2 : m3;
    float inv = m > 0.f ? 127.0f / m : 0.f;
    unsigned int lo = 0, hi = 0;
    #pragma unroll
    for (int nt = 0; nt < 4; ++nt) {
      int q = (int)rintf(acc[nt][r] * inv);
      lo |= ((unsigned int)(q & 255)) << (8 * nt);
    }
    #pragma unroll
    for (int nt = 4; nt < 8; ++nt) {
      int q = (int)rintf(acc[nt][r] * inv);
      hi |= ((unsigned int)(q & 255)) << (8 * (nt - 4));
    }
    int row = row0 + w * 16 + lhi * 4 + r;
    if (row < N_NODES) {
      uint2 p; p.x = lo; p.y = hi;
      *(uint2*)(support_q + (size_t)row * 128 + l15 * 8) = p;
    }
  }
  if (l15 < 4) {
    float m = (l15 == 0) ? m0 : (l15 == 1) ? m1 : (l15 == 2) ? m2 : m3;
    int row = row0 + w * 16 + lhi * 4 + l15;
    if (row < N_NODES) scales[row] = m * (1.0f / 127.0f);
  }
}

// ---------- kernel 2: row_ptr via binary search (edge_row is sorted) ----------
__global__ __launch_bounds__(256) void rowptr_kernel(
    const int* __restrict__ edge_row, int* __restrict__ row_ptr) {
  int r = blockIdx.x * 256 + threadIdx.x;
  if (r > N_NODES) return;
  int lo = 0, hi = N_EDGES;
  while (lo < hi) {
    int mid = (lo + hi) >> 1;
    if (edge_row[mid] < r) lo = mid + 1; else hi = mid;
  }
  row_ptr[r] = lo;  // first edge with row >= r
}

// ---------- kernel 3: CSR SpMM on int8 support ----------
// wave per row; lane = eslot(1b) | fg(5b): 2 edges per gather, 32 lanes x 4 B
// = 128 B (full row) per edge. 8 independent gathers (16 edges) in flight.
// Dequant: w = val * scale[col]; 4x (sext-bfe, cvt, fma).
__global__ __launch_bounds__(256) void spmm_kernel(
    const unsigned char* __restrict__ support_q,  // [N_NODES][128] permuted int8
    const float* __restrict__ scales,             // [N_NODES]
    const int* __restrict__ row_ptr,
    const int* __restrict__ edge_col,
    const float* __restrict__ edge_val,
    const float* __restrict__ bias,
    float* __restrict__ out) {
  int row = (blockIdx.x * 256 + threadIdx.x) >> 6;   // wave-uniform
  row = __builtin_amdgcn_readfirstlane(row);
  if (row >= N_NODES) return;
  const int lane = threadIdx.x & 63;
  const int esl  = lane >> 5;        // edge slot 0..1
  const int fg   = lane & 31;        // feature group: bytes 4fg..4fg+3

  // un-permuted output columns for this lane's 4 bytes
  const int cbase = (fg & 1) * 64 + (fg >> 1);
  const int c0o = cbase, c1o = cbase + 16, c2o = cbase + 32, c3o = cbase + 48;
  const float b0 = bias[c0o], b1 = bias[c1o], b2 = bias[c2o], b3 = bias[c3o];

  int e   = row_ptr[row];
  int end = row_ptr[row + 1];
  float a0 = 0.f, a1 = 0.f, a2 = 0.f, a3 = 0.f;

  while (e < end) {
    const int tm1 = end - 1;
#define EDGE_LD(g) \
    int   ei##g = e + 2 * g + esl; \
    int   j##g  = ei##g < end ? ei##g : tm1; \
    int   c##g  = edge_col[j##g]; \
    float v##g  = ei##g < end ? edge_val[j##g] : 0.f;
    EDGE_LD(0) EDGE_LD(1) EDGE_LD(2) EDGE_LD(3)
    EDGE_LD(4) EDGE_LD(5) EDGE_LD(6) EDGE_LD(7)
#undef EDGE_LD
#define GATH(g) \
    unsigned int s##g = *(const unsigned int*)(support_q + (size_t)c##g * 128 + fg * 4); \
    float sc##g = scales[c##g];
    GATH(0) GATH(1) GATH(2) GATH(3)
    GATH(4) GATH(5) GATH(6) GATH(7)
#undef GATH
#define ACCUM(g) { \
    float wv = v##g * sc##g; \
    a0 += wv * (float)(((int)(s##g << 24)) >> 24); \
    a1 += wv * (float)(((int)(s##g << 16)) >> 24); \
    a2 += wv * (float)(((int)(s##g <<  8)) >> 24); \
    a3 += wv * (float)(((int)s##g) >> 24); }
    ACCUM(0) ACCUM(1) ACCUM(2) ACCUM(3)
    ACCUM(4) ACCUM(5) ACCUM(6) ACCUM(7)
#undef ACCUM
    e += 16;
  }

  // combine the two edge-slot halves
  a0 += __shfl_xor(a0, 32, 64);
  a1 += __shfl_xor(a1, 32, 64);
  a2 += __shfl_xor(a2, 32, 64);
  a3 += __shfl_xor(a3, 32, 64);

  if (lane < 32) {
    float* op = out + (size_t)row * OUT_F;
    op[c0o] = a0 + b0;
    op[c1o] = a1 + b1;
    op[c2o] = a2 + b2;
    op[c3o] = a3 + b3;
  }
}

// ---------- launch ----------
extern "C" void kernel_launch(void* const* d_in, const int* in_sizes, int n_in,
                              void* d_out, int out_size, void* d_ws, size_t ws_size,
                              hipStream_t stream) {
  const float* x        = (const float*)d_in[0];
  const int*   edge_row = (const int*)  d_in[1];
  const int*   edge_col = (const int*)  d_in[2];
  const float* edge_val = (const float*)d_in[3];
  const float* weight   = (const float*)d_in[4];
  const float* bias     = (const float*)d_in[5];
  float* out = (float*)d_out;

  unsigned char* ws = (unsigned char*)d_ws;
  size_t sq_bytes = (size_t)N_NODES * 128;                       // 12.8 MB int8
  unsigned char* support_q = ws;
  size_t rp_off = (sq_bytes + 255) & ~(size_t)255;
  int* row_ptr = (int*)(ws + rp_off);
  size_t wt_off = (rp_off + (size_t)(N_NODES + 1) * 4 + 255) & ~(size_t)255;
  unsigned short* wt = (unsigned short*)(ws + wt_off);
  size_t sc_off = (wt_off + (size_t)IN_F * OUT_F * 2 + 255) & ~(size_t)255;
  float* scales = (float*)(ws + sc_off);

  hipLaunchKernelGGL(rowptr_kernel, dim3((N_NODES + 1 + 255) / 256), dim3(256), 0, stream,
                     edge_row, row_ptr);
  hipLaunchKernelGGL(wconv_kernel, dim3(128), dim3(256), 0, stream,
                     weight, wt);
  hipLaunchKernelGGL(gemm_xw_mfma, dim3((N_NODES + 63) / 64), dim3(256), 0, stream,
                     x, wt, support_q, scales);
  hipLaunchKernelGGL(spmm_kernel, dim3(N_NODES / 4), dim3(256), 0, stream,
                     support_q, scales, row_ptr, edge_col, edge_val, bias, out);
}